// Round 1
// baseline (414.607 us; speedup 1.0000x reference)
//
#include <hip/hip_runtime.h>

#define HID 64
#define TT  128
#define NROWS 8192

// d_ws table layout (floats): GA[7][192] (b_f folded in), GB[4][192], GC[5][192], WB[192]
// xg_i(t) = GA[actor][i] + GB[action][i] + GC[street][i] + WB[i]*bet
__global__ __launch_bounds__(256) void setup_tables(
    const float* __restrict__ E_actor, const float* __restrict__ E_action,
    const float* __restrict__ E_street, const float* __restrict__ W_proj,
    const float* __restrict__ b_proj, const float* __restrict__ W_ih,
    const float* __restrict__ b_ih, float* __restrict__ tab)
{
    int j = threadIdx.x;
    if (j >= 192) return;
    // W_f[j][m] = sum_k W_ih[j,k] * W_proj[k,m]   (k<32, m<21)
    float wf[21];
    #pragma unroll
    for (int m = 0; m < 21; m++) wf[m] = 0.f;
    float bf = b_ih[j];
    for (int k = 0; k < 32; k++) {
        float w = W_ih[j * 32 + k];
        bf += w * b_proj[k];
        #pragma unroll
        for (int m = 0; m < 21; m++) wf[m] += w * W_proj[k * 21 + m];
    }
    for (int a = 0; a < 7; a++) {
        float s = bf;
        #pragma unroll
        for (int m = 0; m < 8; m++) s += wf[m] * E_actor[a * 8 + m];
        tab[a * 192 + j] = s;
    }
    for (int b = 0; b < 4; b++) {
        float s = 0.f;
        #pragma unroll
        for (int m = 0; m < 8; m++) s += wf[8 + m] * E_action[b * 8 + m];
        tab[(7 + b) * 192 + j] = s;
    }
    for (int c = 0; c < 5; c++) {
        float s = 0.f;
        #pragma unroll
        for (int m = 0; m < 4; m++) s += wf[16 + m] * E_street[c * 4 + m];
        tab[(11 + c) * 192 + j] = s;
    }
    tab[16 * 192 + j] = wf[20];
}

// One wave per batch row. Lane i owns hidden index i and W_hh rows {i, i+64, i+128}
// in registers (48 float4 = 192 VGPR). h broadcast via per-wave LDS buffer.
__global__ __launch_bounds__(256, 2) void gru_fused(
    const int* __restrict__ actor_ids, const int* __restrict__ action_ids,
    const int* __restrict__ street_ids, const float* __restrict__ bet,
    const int* __restrict__ mask, const float* __restrict__ W_hh,
    const float* __restrict__ b_hh, const float* __restrict__ tab,
    float* __restrict__ out)
{
    __shared__ float Tl[17 * 192];       // 13056 B tables
    __shared__ float hbuf[4][HID];       // per-wave hidden state
    __shared__ float betb[4][TT];
    __shared__ int   idxb[4][TT];

    const int tid = threadIdx.x;
    const int wv  = tid >> 6;
    const int ln  = tid & 63;

    for (int i = tid; i < 17 * 192; i += 256) Tl[i] = tab[i];
    __syncthreads();

    // W_hh is [192][64] row-major fp32; lane ln takes rows ln, ln+64, ln+128.
    float4 Wr[16], Wz[16], Wn[16];
    {
        const float4* g = (const float4*)W_hh;
        #pragma unroll
        for (int q = 0; q < 16; q++) {
            Wr[q] = g[ln * 16 + q];
            Wz[q] = g[(ln + 64) * 16 + q];
            Wn[q] = g[(ln + 128) * 16 + q];
        }
    }
    const float bhr = b_hh[ln], bhz = b_hh[ln + 64], bhn = b_hh[ln + 128];

    const int row  = blockIdx.x * 4 + wv;      // 2048 blocks -> one row per wave
    const int base = row * TT;

    // Stage packed ids + bet for this row into LDS; length via ballot popcount.
    int   a0 = actor_ids[base + ln],   a1 = actor_ids[base + 64 + ln];
    int   c0 = action_ids[base + ln],  c1 = action_ids[base + 64 + ln];
    int   s0 = street_ids[base + ln],  s1 = street_ids[base + 64 + ln];
    float f0 = bet[base + ln],         f1 = bet[base + 64 + ln];
    int   m0 = mask[base + ln],        m1 = mask[base + 64 + ln];
    idxb[wv][ln]      = a0 | (c0 << 3) | (s0 << 5);
    idxb[wv][ln + 64] = a1 | (c1 << 3) | (s1 << 5);
    betb[wv][ln]      = f0;
    betb[wv][ln + 64] = f1;
    const int L = __popcll(__ballot(m0 != 0)) + __popcll(__ballot(m1 != 0));

    float h = 0.f;
    hbuf[wv][ln] = 0.f;

    const float* TA = Tl;                // [7][192]
    const float* TB = Tl + 7 * 192;      // [4][192]
    const float* TC = Tl + 11 * 192;     // [5][192]
    const float* WB = Tl + 16 * 192;     // [192]
    const float4* h4 = (const float4*)hbuf[wv];

    for (int t = 0; t < L; t++) {
        const int   p  = idxb[wv][t];    // broadcast read
        const float bt = betb[wv][t];
        const int a  = p & 7;
        const int b2 = (p >> 3) & 3;
        const int c  = (p >> 5) & 7;

        float xr = TA[a * 192 + ln]       + TB[b2 * 192 + ln]       + TC[c * 192 + ln]       + WB[ln] * bt;
        float xz = TA[a * 192 + 64 + ln]  + TB[b2 * 192 + 64 + ln]  + TC[c * 192 + 64 + ln]  + WB[64 + ln] * bt;
        float xn = TA[a * 192 + 128 + ln] + TB[b2 * 192 + 128 + ln] + TC[c * 192 + 128 + ln] + WB[128 + ln] * bt;

        float hr = bhr, hz = bhz, hn = bhn;
        #pragma unroll
        for (int q = 0; q < 16; q++) {
            const float4 hv = h4[q];     // same-address broadcast across lanes
            hr = fmaf(Wr[q].x, hv.x, hr);
            hz = fmaf(Wz[q].x, hv.x, hz);
            hn = fmaf(Wn[q].x, hv.x, hn);
            hr = fmaf(Wr[q].y, hv.y, hr);
            hz = fmaf(Wz[q].y, hv.y, hz);
            hn = fmaf(Wn[q].y, hv.y, hn);
            hr = fmaf(Wr[q].z, hv.z, hr);
            hz = fmaf(Wz[q].z, hv.z, hz);
            hn = fmaf(Wn[q].z, hv.z, hn);
            hr = fmaf(Wr[q].w, hv.w, hr);
            hz = fmaf(Wz[q].w, hv.w, hz);
            hn = fmaf(Wn[q].w, hv.w, hn);
        }

        const float r = __builtin_amdgcn_rcpf(1.f + __expf(-(xr + hr)));
        const float z = __builtin_amdgcn_rcpf(1.f + __expf(-(xz + hz)));
        const float ny = xn + r * hn;
        const float n = 1.f - 2.f * __builtin_amdgcn_rcpf(1.f + __expf(2.f * ny));
        h = n + z * (h - n);             // (1-z)*n + z*h
        hbuf[wv][ln] = h;                // wave-synchronous update for next step
    }

    out[row * HID + ln] = h;
}

extern "C" void kernel_launch(void* const* d_in, const int* in_sizes, int n_in,
                              void* d_out, int out_size, void* d_ws, size_t ws_size,
                              hipStream_t stream) {
    const int*   actor_ids  = (const int*)d_in[0];
    const int*   action_ids = (const int*)d_in[1];
    const int*   street_ids = (const int*)d_in[2];
    const float* bet        = (const float*)d_in[3];
    const int*   vmask      = (const int*)d_in[4];
    const float* E_actor    = (const float*)d_in[5];
    const float* E_action   = (const float*)d_in[6];
    const float* E_street   = (const float*)d_in[7];
    const float* W_proj     = (const float*)d_in[8];
    const float* b_proj     = (const float*)d_in[9];
    const float* W_ih       = (const float*)d_in[10];
    const float* W_hh       = (const float*)d_in[11];
    const float* b_ih       = (const float*)d_in[12];
    const float* b_hh       = (const float*)d_in[13];
    float*       out        = (float*)d_out;
    float*       tab        = (float*)d_ws;

    setup_tables<<<1, 256, 0, stream>>>(E_actor, E_action, E_street, W_proj,
                                        b_proj, W_ih, b_ih, tab);
    gru_fused<<<NROWS / 4, 256, 0, stream>>>(actor_ids, action_ids, street_ids,
                                             bet, vmask, W_hh, b_hh, tab, out);
}

// Round 2
// 328.612 us; speedup vs baseline: 1.2617x; 1.2617x over previous
//
#include <hip/hip_runtime.h>

#define HID 64
#define TT  128
#define NROWS 8192

typedef _Float16 h2 __attribute__((ext_vector_type(2)));

// d_ws table layout (floats): [17][192]:
//   rows 0..6  = GA[actor][g*64+hid]  (b_f folded in)
//   rows 7..10 = GB[action][...]
//   rows 11..15= GC[street][...]
//   row 16     = WB (bet weight column of fused W_f)
// xg(gate g, hid i) = GA[a][g*64+i] + GB[c][g*64+i] + GC[s][g*64+i] + WB[g*64+i]*bet
__global__ __launch_bounds__(256) void setup_tables(
    const float* __restrict__ E_actor, const float* __restrict__ E_action,
    const float* __restrict__ E_street, const float* __restrict__ W_proj,
    const float* __restrict__ b_proj, const float* __restrict__ W_ih,
    const float* __restrict__ b_ih, float* __restrict__ tab)
{
    int j = threadIdx.x;
    if (j >= 192) return;
    // W_f[j][m] = sum_k W_ih[j,k] * W_proj[k,m]   (k<32, m<21)
    float wf[21];
    #pragma unroll
    for (int m = 0; m < 21; m++) wf[m] = 0.f;
    float bf = b_ih[j];
    for (int k = 0; k < 32; k++) {
        float w = W_ih[j * 32 + k];
        bf += w * b_proj[k];
        #pragma unroll
        for (int m = 0; m < 21; m++) wf[m] += w * W_proj[k * 21 + m];
    }
    for (int a = 0; a < 7; a++) {
        float s = bf;
        #pragma unroll
        for (int m = 0; m < 8; m++) s += wf[m] * E_actor[a * 8 + m];
        tab[a * 192 + j] = s;
    }
    for (int b = 0; b < 4; b++) {
        float s = 0.f;
        #pragma unroll
        for (int m = 0; m < 8; m++) s += wf[8 + m] * E_action[b * 8 + m];
        tab[(7 + b) * 192 + j] = s;
    }
    for (int c = 0; c < 5; c++) {
        float s = 0.f;
        #pragma unroll
        for (int m = 0; m < 4; m++) s += wf[16 + m] * E_street[c * 4 + m];
        tab[(11 + c) * 192 + j] = s;
    }
    tab[16 * 192 + j] = wf[20];
}

// One wave per batch row. Lane i owns hidden index i; W_hh rows {i,i+64,i+128}
// held as packed f16 pairs in registers (96 VGPRs). Matvec via v_dot2_f32_f16
// (2 MACs/instr, fp32 accumulate). h state stays fp32 in registers; only the
// LDS broadcast copy is f16.
__global__ __launch_bounds__(256, 3) void gru_fused(
    const int* __restrict__ actor_ids, const int* __restrict__ action_ids,
    const int* __restrict__ street_ids, const float* __restrict__ bet,
    const int* __restrict__ mask, const float* __restrict__ W_hh,
    const float* __restrict__ b_hh, const float* __restrict__ tab,
    float* __restrict__ out)
{
    // Interleaved tables: Tl[id*192 + hid*3 + gate]
    __shared__ float Tl[16 * 192];
    __shared__ __align__(16) _Float16 hbuf[4][HID];   // per-wave f16 hidden copy
    __shared__ int2 pb[4][TT];                        // {packed ids, bet bits}

    const int tid = threadIdx.x;
    const int wv  = tid >> 6;
    const int ln  = tid & 63;

    for (int i = tid; i < 16 * 192; i += 256) {
        int id = i / 192, j = i % 192;
        Tl[id * 192 + (j & 63) * 3 + (j >> 6)] = tab[i];   // coalesced read
    }
    __syncthreads();

    // W_hh is [192][64] row-major fp32; lane ln takes rows ln, ln+64, ln+128,
    // converted to packed f16 pairs.
    h2 Wr[32], Wz[32], Wn[32];
    {
        const float4* g = (const float4*)W_hh;
        #pragma unroll
        for (int q = 0; q < 16; q++) {
            float4 wr = g[ln * 16 + q];
            float4 wz = g[(ln + 64) * 16 + q];
            float4 wn = g[(ln + 128) * 16 + q];
            Wr[2 * q]     = h2{(_Float16)wr.x, (_Float16)wr.y};
            Wr[2 * q + 1] = h2{(_Float16)wr.z, (_Float16)wr.w};
            Wz[2 * q]     = h2{(_Float16)wz.x, (_Float16)wz.y};
            Wz[2 * q + 1] = h2{(_Float16)wz.z, (_Float16)wz.w};
            Wn[2 * q]     = h2{(_Float16)wn.x, (_Float16)wn.y};
            Wn[2 * q + 1] = h2{(_Float16)wn.z, (_Float16)wn.w};
        }
    }
    const float bhr = b_hh[ln], bhz = b_hh[ln + 64], bhn = b_hh[ln + 128];
    const float wbr = tab[16 * 192 + ln];
    const float wbz = tab[16 * 192 + 64 + ln];
    const float wbn = tab[16 * 192 + 128 + ln];

    const int row  = blockIdx.x * 4 + wv;      // 2048 blocks -> one row per wave
    const int base = row * TT;

    // Stage packed ids + bet; length via ballot popcount (prefix mask).
    {
        int   a0 = actor_ids[base + ln],   a1 = actor_ids[base + 64 + ln];
        int   c0 = action_ids[base + ln],  c1 = action_ids[base + 64 + ln];
        int   s0 = street_ids[base + ln],  s1 = street_ids[base + 64 + ln];
        float f0 = bet[base + ln],         f1 = bet[base + 64 + ln];
        pb[wv][ln]      = make_int2(a0 | (c0 << 3) | (s0 << 5), __float_as_int(f0));
        pb[wv][ln + 64] = make_int2(a1 | (c1 << 3) | (s1 << 5), __float_as_int(f1));
    }
    const int m0 = mask[base + ln], m1 = mask[base + 64 + ln];
    const int L = __popcll(__ballot(m0 != 0)) + __popcll(__ballot(m1 != 0));

    float h = 0.f;
    hbuf[wv][ln] = (_Float16)0.f;

    const float4* h4 = (const float4*)hbuf[wv];   // 8 f16 per float4 chunk

    for (int t = 0; t < L; t++) {
        const int2  pbt = pb[wv][t];              // broadcast ds_read_b64
        const float bt  = __int_as_float(pbt.y);
        const int a  = pbt.x & 7;
        const int b2 = (pbt.x >> 3) & 3;
        const int c  = (pbt.x >> 5) & 7;

        const float* ta = &Tl[a * 192 + ln * 3];
        const float* tb = &Tl[(7 + b2) * 192 + ln * 3];
        const float* tc = &Tl[(11 + c) * 192 + ln * 3];
        const float xr = ta[0] + tb[0] + tc[0] + wbr * bt;
        const float xz = ta[1] + tb[1] + tc[1] + wbz * bt;
        const float xn = ta[2] + tb[2] + tc[2] + wbn * bt;

        float hr = bhr, hz = bhz, hn = bhn;
        #pragma unroll
        for (int q = 0; q < 8; q++) {
            float4 hv = h4[q];                    // broadcast ds_read_b128
            const h2* hp = (const h2*)&hv;        // 4 packed f16 pairs
            #pragma unroll
            for (int j = 0; j < 4; j++) {
                hr = __builtin_amdgcn_fdot2(Wr[4 * q + j], hp[j], hr, false);
                hz = __builtin_amdgcn_fdot2(Wz[4 * q + j], hp[j], hz, false);
                hn = __builtin_amdgcn_fdot2(Wn[4 * q + j], hp[j], hn, false);
            }
        }

        const float r = __builtin_amdgcn_rcpf(1.f + __expf(-(xr + hr)));
        const float z = __builtin_amdgcn_rcpf(1.f + __expf(-(xz + hz)));
        const float ny = xn + r * hn;
        const float n = 1.f - 2.f * __builtin_amdgcn_rcpf(1.f + __expf(2.f * ny));
        h = n + z * (h - n);                      // (1-z)*n + z*h, fp32 state
        hbuf[wv][ln] = (_Float16)h;               // f16 copy for next broadcast
    }

    out[row * HID + ln] = h;
}

extern "C" void kernel_launch(void* const* d_in, const int* in_sizes, int n_in,
                              void* d_out, int out_size, void* d_ws, size_t ws_size,
                              hipStream_t stream) {
    const int*   actor_ids  = (const int*)d_in[0];
    const int*   action_ids = (const int*)d_in[1];
    const int*   street_ids = (const int*)d_in[2];
    const float* bet        = (const float*)d_in[3];
    const int*   vmask      = (const int*)d_in[4];
    const float* E_actor    = (const float*)d_in[5];
    const float* E_action   = (const float*)d_in[6];
    const float* E_street   = (const float*)d_in[7];
    const float* W_proj     = (const float*)d_in[8];
    const float* b_proj     = (const float*)d_in[9];
    const float* W_ih       = (const float*)d_in[10];
    const float* W_hh       = (const float*)d_in[11];
    const float* b_ih       = (const float*)d_in[12];
    const float* b_hh       = (const float*)d_in[13];
    float*       out        = (float*)d_out;
    float*       tab        = (float*)d_ws;

    setup_tables<<<1, 256, 0, stream>>>(E_actor, E_action, E_street, W_proj,
                                        b_proj, W_ih, b_ih, tab);
    gru_fused<<<NROWS / 4, 256, 0, stream>>>(actor_ids, action_ids, street_ids,
                                             bet, vmask, W_hh, b_hh, tab, out);
}

// Round 3
// 327.509 us; speedup vs baseline: 1.2659x; 1.0034x over previous
//
#include <hip/hip_runtime.h>

#define HID 64
#define TT  128
#define NROWS 8192

typedef _Float16 h2 __attribute__((ext_vector_type(2)));

// d_ws table layout (floats): [17][192]:
//   rows 0..6  = GA[actor][g*64+hid]  (b_f folded in)
//   rows 7..10 = GB[action][...]
//   rows 11..15= GC[street][...]
//   row 16     = WB (bet weight column of fused W_f)
// xg(gate g, hid i) = GA[a][g*64+i] + GB[c][g*64+i] + GC[s][g*64+i] + WB[g*64+i]*bet
__global__ __launch_bounds__(256) void setup_tables(
    const float* __restrict__ E_actor, const float* __restrict__ E_action,
    const float* __restrict__ E_street, const float* __restrict__ W_proj,
    const float* __restrict__ b_proj, const float* __restrict__ W_ih,
    const float* __restrict__ b_ih, float* __restrict__ tab)
{
    int j = threadIdx.x;
    if (j >= 192) return;
    // W_f[j][m] = sum_k W_ih[j,k] * W_proj[k,m]   (k<32, m<21)
    float wf[21];
    #pragma unroll
    for (int m = 0; m < 21; m++) wf[m] = 0.f;
    float bf = b_ih[j];
    for (int k = 0; k < 32; k++) {
        float w = W_ih[j * 32 + k];
        bf += w * b_proj[k];
        #pragma unroll
        for (int m = 0; m < 21; m++) wf[m] += w * W_proj[k * 21 + m];
    }
    for (int a = 0; a < 7; a++) {
        float s = bf;
        #pragma unroll
        for (int m = 0; m < 8; m++) s += wf[m] * E_actor[a * 8 + m];
        tab[a * 192 + j] = s;
    }
    for (int b = 0; b < 4; b++) {
        float s = 0.f;
        #pragma unroll
        for (int m = 0; m < 8; m++) s += wf[8 + m] * E_action[b * 8 + m];
        tab[(7 + b) * 192 + j] = s;
    }
    for (int c = 0; c < 5; c++) {
        float s = 0.f;
        #pragma unroll
        for (int m = 0; m < 4; m++) s += wf[16 + m] * E_street[c * 4 + m];
        tab[(11 + c) * 192 + j] = s;
    }
    tab[16 * 192 + j] = wf[20];
}

// One wave per batch row. Lane i owns hidden index i; W_hh rows {i,i+64,i+128}
// held as packed f16 pairs in registers (96 VGPRs). Matvec via v_dot2_f32_f16.
// __launch_bounds__(256,2): 256-reg/wave budget so the W arrays stay in arch
// VGPRs — (256,3)'s 170-reg budget demoted them to AGPRs, costing one
// v_accvgpr_read per fdot2 (R1/R2 regression root cause).
__global__ __launch_bounds__(256, 2) void gru_fused(
    const int* __restrict__ actor_ids, const int* __restrict__ action_ids,
    const int* __restrict__ street_ids, const float* __restrict__ bet,
    const int* __restrict__ mask, const float* __restrict__ W_hh,
    const float* __restrict__ b_hh, const float* __restrict__ tab,
    float* __restrict__ out)
{
    // Interleaved tables: Tl[id*192 + hid*3 + gate]
    __shared__ float Tl[16 * 192];
    __shared__ __align__(16) _Float16 hbuf[4][HID];   // per-wave f16 hidden copy
    __shared__ int2 pb[4][TT];                        // {packed ids, bet bits}

    const int tid = threadIdx.x;
    const int wv  = tid >> 6;
    const int ln  = tid & 63;

    for (int i = tid; i < 16 * 192; i += 256) {
        int id = i / 192, j = i % 192;
        Tl[id * 192 + (j & 63) * 3 + (j >> 6)] = tab[i];   // coalesced read
    }
    __syncthreads();

    // W_hh is [192][64] row-major fp32; lane ln takes rows ln, ln+64, ln+128,
    // converted to packed f16 pairs.
    h2 Wr[32], Wz[32], Wn[32];
    {
        const float4* g = (const float4*)W_hh;
        #pragma unroll
        for (int q = 0; q < 16; q++) {
            float4 wr = g[ln * 16 + q];
            float4 wz = g[(ln + 64) * 16 + q];
            float4 wn = g[(ln + 128) * 16 + q];
            Wr[2 * q]     = h2{(_Float16)wr.x, (_Float16)wr.y};
            Wr[2 * q + 1] = h2{(_Float16)wr.z, (_Float16)wr.w};
            Wz[2 * q]     = h2{(_Float16)wz.x, (_Float16)wz.y};
            Wz[2 * q + 1] = h2{(_Float16)wz.z, (_Float16)wz.w};
            Wn[2 * q]     = h2{(_Float16)wn.x, (_Float16)wn.y};
            Wn[2 * q + 1] = h2{(_Float16)wn.z, (_Float16)wn.w};
        }
    }
    const float bhr = b_hh[ln], bhz = b_hh[ln + 64], bhn = b_hh[ln + 128];
    const float wbr = tab[16 * 192 + ln];
    const float wbz = tab[16 * 192 + 64 + ln];
    const float wbn = tab[16 * 192 + 128 + ln];

    const int row  = blockIdx.x * 4 + wv;      // 2048 blocks -> one row per wave
    const int base = row * TT;

    // Stage packed ids + bet; length via ballot popcount (prefix mask).
    {
        int   a0 = actor_ids[base + ln],   a1 = actor_ids[base + 64 + ln];
        int   c0 = action_ids[base + ln],  c1 = action_ids[base + 64 + ln];
        int   s0 = street_ids[base + ln],  s1 = street_ids[base + 64 + ln];
        float f0 = bet[base + ln],         f1 = bet[base + 64 + ln];
        pb[wv][ln]      = make_int2(a0 | (c0 << 3) | (s0 << 5), __float_as_int(f0));
        pb[wv][ln + 64] = make_int2(a1 | (c1 << 3) | (s1 << 5), __float_as_int(f1));
    }
    const int m0 = mask[base + ln], m1 = mask[base + 64 + ln];
    const int L = __popcll(__ballot(m0 != 0)) + __popcll(__ballot(m1 != 0));

    float h = 0.f;
    hbuf[wv][ln] = (_Float16)0.f;

    const float4* h4 = (const float4*)hbuf[wv];   // 8 f16 per float4 chunk

    for (int t = 0; t < L; t++) {
        const int2  pbt = pb[wv][t];              // broadcast ds_read_b64
        const float bt  = __int_as_float(pbt.y);
        const int a  = pbt.x & 7;
        const int b2 = (pbt.x >> 3) & 3;
        const int c  = (pbt.x >> 5) & 7;

        const float* ta = &Tl[a * 192 + ln * 3];
        const float* tb = &Tl[(7 + b2) * 192 + ln * 3];
        const float* tc = &Tl[(11 + c) * 192 + ln * 3];
        const float xr = ta[0] + tb[0] + tc[0] + wbr * bt;
        const float xz = ta[1] + tb[1] + tc[1] + wbz * bt;
        const float xn = ta[2] + tb[2] + tc[2] + wbn * bt;

        float hr = bhr, hz = bhz, hn = bhn;
        #pragma unroll
        for (int q = 0; q < 8; q++) {
            float4 hv = h4[q];                    // broadcast ds_read_b128
            const h2* hp = (const h2*)&hv;        // 4 packed f16 pairs
            #pragma unroll
            for (int j = 0; j < 4; j++) {
                hr = __builtin_amdgcn_fdot2(Wr[4 * q + j], hp[j], hr, false);
                hz = __builtin_amdgcn_fdot2(Wz[4 * q + j], hp[j], hz, false);
                hn = __builtin_amdgcn_fdot2(Wn[4 * q + j], hp[j], hn, false);
            }
        }

        const float r = __builtin_amdgcn_rcpf(1.f + __expf(-(xr + hr)));
        const float z = __builtin_amdgcn_rcpf(1.f + __expf(-(xz + hz)));
        const float ny = xn + r * hn;
        const float n = 1.f - 2.f * __builtin_amdgcn_rcpf(1.f + __expf(2.f * ny));
        h = n + z * (h - n);                      // (1-z)*n + z*h, fp32 state
        hbuf[wv][ln] = (_Float16)h;               // f16 copy for next broadcast
    }

    out[row * HID + ln] = h;
}

extern "C" void kernel_launch(void* const* d_in, const int* in_sizes, int n_in,
                              void* d_out, int out_size, void* d_ws, size_t ws_size,
                              hipStream_t stream) {
    const int*   actor_ids  = (const int*)d_in[0];
    const int*   action_ids = (const int*)d_in[1];
    const int*   street_ids = (const int*)d_in[2];
    const float* bet        = (const float*)d_in[3];
    const int*   vmask      = (const int*)d_in[4];
    const float* E_actor    = (const float*)d_in[5];
    const float* E_action   = (const float*)d_in[6];
    const float* E_street   = (const float*)d_in[7];
    const float* W_proj     = (const float*)d_in[8];
    const float* b_proj     = (const float*)d_in[9];
    const float* W_ih       = (const float*)d_in[10];
    const float* W_hh       = (const float*)d_in[11];
    const float* b_ih       = (const float*)d_in[12];
    const float* b_hh       = (const float*)d_in[13];
    float*       out        = (float*)d_out;
    float*       tab        = (float*)d_ws;

    setup_tables<<<1, 256, 0, stream>>>(E_actor, E_action, E_street, W_proj,
                                        b_proj, W_ih, b_ih, tab);
    gru_fused<<<NROWS / 4, 256, 0, stream>>>(actor_ids, action_ids, street_ids,
                                             bet, vmask, W_hh, b_hh, tab, out);
}

// Round 4
// 305.159 us; speedup vs baseline: 1.3587x; 1.0732x over previous
//
#include <hip/hip_runtime.h>

#define HID 64
#define TT  128
#define NROWS 8192

typedef _Float16 h2 __attribute__((ext_vector_type(2)));

// d_ws byte layout:
//   WS_TAB  : 17*192 f32 fused xg tables (GA/GB/GC rows 0..15, WB row 16)
//   WS_W16  : 192*64 f16 pre-converted W_hh (row-major)
//   WS_LROW : 8192 i32 per-row valid length
//   WS_ORDER: 8192 i32 row indices sorted ascending by L (counting sort)
//   WS_HIST : 129 i32 histogram -> exclusive prefix -> scatter cursors
#define WS_TAB   0
#define WS_W16   13056
#define WS_LROW  37632
#define WS_ORDER 70400
#define WS_HIST  103168

// xg(gate g, hid i) = GA[a][g*64+i] + GB[c][g*64+i] + GC[s][g*64+i] + WB[g*64+i]*bet
__global__ __launch_bounds__(256) void setup_tables(
    const float* __restrict__ E_actor, const float* __restrict__ E_action,
    const float* __restrict__ E_street, const float* __restrict__ W_proj,
    const float* __restrict__ b_proj, const float* __restrict__ W_ih,
    const float* __restrict__ b_ih, const float* __restrict__ W_hh,
    float* __restrict__ tab, _Float16* __restrict__ W16)
{
    int j = threadIdx.x;
    if (j >= 192) return;
    // W_f[j][m] = sum_k W_ih[j,k] * W_proj[k,m]   (k<32, m<21)
    float wf[21];
    #pragma unroll
    for (int m = 0; m < 21; m++) wf[m] = 0.f;
    float bf = b_ih[j];
    for (int k = 0; k < 32; k++) {
        float w = W_ih[j * 32 + k];
        bf += w * b_proj[k];
        #pragma unroll
        for (int m = 0; m < 21; m++) wf[m] += w * W_proj[k * 21 + m];
    }
    for (int a = 0; a < 7; a++) {
        float s = bf;
        #pragma unroll
        for (int m = 0; m < 8; m++) s += wf[m] * E_actor[a * 8 + m];
        tab[a * 192 + j] = s;
    }
    for (int b = 0; b < 4; b++) {
        float s = 0.f;
        #pragma unroll
        for (int m = 0; m < 8; m++) s += wf[8 + m] * E_action[b * 8 + m];
        tab[(7 + b) * 192 + j] = s;
    }
    for (int c = 0; c < 5; c++) {
        float s = 0.f;
        #pragma unroll
        for (int m = 0; m < 4; m++) s += wf[16 + m] * E_street[c * 4 + m];
        tab[(11 + c) * 192 + j] = s;
    }
    tab[16 * 192 + j] = wf[20];
    // pre-convert W_hh row j to f16 (kills the f32 staging pressure spike that
    // forced AGPR demotion of the W registers in R1-R3)
    for (int k = 0; k < HID; k++) W16[j * HID + k] = (_Float16)W_hh[j * HID + k];
}

// one wave per row: L via ballot popcount of the prefix mask + histogram
__global__ __launch_bounds__(256) void len_hist(
    const int* __restrict__ mask, int* __restrict__ Lrow, int* __restrict__ hist)
{
    const int wv = threadIdx.x >> 6, ln = threadIdx.x & 63;
    const int row = blockIdx.x * 4 + wv, base = row * TT;
    const int m0 = mask[base + ln], m1 = mask[base + 64 + ln];
    const int L = __popcll(__ballot(m0 != 0)) + __popcll(__ballot(m1 != 0));
    if (ln == 0) { Lrow[row] = L; atomicAdd(&hist[L], 1); }
}

__global__ void scan_hist(int* __restrict__ hist)
{
    if (threadIdx.x == 0) {
        int run = 0;
        for (int i = 0; i <= TT; i++) { int t = hist[i]; hist[i] = run; run += t; }
    }
}

__global__ __launch_bounds__(256) void scatter_rows(
    const int* __restrict__ Lrow, int* __restrict__ hist, int* __restrict__ order)
{
    const int r = blockIdx.x * 256 + threadIdx.x;
    const int pos = atomicAdd(&hist[Lrow[r]], 1);
    order[pos] = r;
}

// One wave per (length-sorted) row. Lane i owns hidden index i; W_hh rows
// {i,i+64,i+128} as packed f16 pairs loaded DIRECTLY from pre-converted W16
// (24 uint4 loads, no f32 staging). Matvec via v_dot2_f32_f16, fp32 h state.
__global__ __launch_bounds__(256, 3) void gru_fused(
    const int* __restrict__ actor_ids, const int* __restrict__ action_ids,
    const int* __restrict__ street_ids, const float* __restrict__ bet,
    const _Float16* __restrict__ W16, const float* __restrict__ b_hh,
    const float* __restrict__ tab, const int* __restrict__ order,
    const int* __restrict__ Lrow, float* __restrict__ out)
{
    // Interleaved tables: Tl[id*192 + hid*3 + gate]
    __shared__ float Tl[16 * 192];
    __shared__ __align__(16) _Float16 hbuf[4][HID];   // per-wave f16 hidden copy
    __shared__ int2 pb[4][TT];                        // {packed ids, bet bits}

    const int tid = threadIdx.x;
    const int wv  = tid >> 6;
    const int ln  = tid & 63;

    for (int i = tid; i < 16 * 192; i += 256) {
        int id = i / 192, j = i % 192;
        Tl[id * 192 + (j & 63) * 3 + (j >> 6)] = tab[i];   // coalesced read
    }
    __syncthreads();

    // Load packed f16 W rows ln, ln+64, ln+128 straight into registers.
    h2 Wr[32], Wz[32], Wn[32];
    {
        const uint4* wg = (const uint4*)W16;     // 8 uint4 per 64-f16 row
        uint4* r4 = (uint4*)Wr;
        uint4* z4 = (uint4*)Wz;
        uint4* n4 = (uint4*)Wn;
        #pragma unroll
        for (int q = 0; q < 8; q++) {
            r4[q] = wg[ln * 8 + q];
            z4[q] = wg[(ln + 64) * 8 + q];
            n4[q] = wg[(ln + 128) * 8 + q];
        }
    }
    const float bhr = b_hh[ln], bhz = b_hh[ln + 64], bhn = b_hh[ln + 128];
    const float wbr = tab[16 * 192 + ln];
    const float wbz = tab[16 * 192 + 64 + ln];
    const float wbn = tab[16 * 192 + 128 + ln];

    const int slot = blockIdx.x * 4 + wv;      // sorted slot -> original row
    const int row  = order[slot];
    const int L    = Lrow[row];
    const int base = row * TT;

    // Stage packed ids + bet for this row.
    {
        int   a0 = actor_ids[base + ln],   a1 = actor_ids[base + 64 + ln];
        int   c0 = action_ids[base + ln],  c1 = action_ids[base + 64 + ln];
        int   s0 = street_ids[base + ln],  s1 = street_ids[base + 64 + ln];
        float f0 = bet[base + ln],         f1 = bet[base + 64 + ln];
        pb[wv][ln]      = make_int2(a0 | (c0 << 3) | (s0 << 5), __float_as_int(f0));
        pb[wv][ln + 64] = make_int2(a1 | (c1 << 3) | (s1 << 5), __float_as_int(f1));
    }

    float h = 0.f;
    hbuf[wv][ln] = (_Float16)0.f;

    const float4* h4 = (const float4*)hbuf[wv];   // 8 f16 per float4 chunk

    for (int t = 0; t < L; t++) {
        const int2  pbt = pb[wv][t];              // broadcast ds_read_b64
        const float bt  = __int_as_float(pbt.y);
        const int a  = pbt.x & 7;
        const int b2 = (pbt.x >> 3) & 3;
        const int c  = (pbt.x >> 5) & 7;

        const float* ta = &Tl[a * 192 + ln * 3];
        const float* tb = &Tl[(7 + b2) * 192 + ln * 3];
        const float* tc = &Tl[(11 + c) * 192 + ln * 3];
        const float xr = ta[0] + tb[0] + tc[0] + wbr * bt;
        const float xz = ta[1] + tb[1] + tc[1] + wbz * bt;
        const float xn = ta[2] + tb[2] + tc[2] + wbn * bt;

        float hr = bhr, hz = bhz, hn = bhn;
        #pragma unroll
        for (int q = 0; q < 8; q++) {
            float4 hv = h4[q];                    // broadcast ds_read_b128
            const h2* hp = (const h2*)&hv;        // 4 packed f16 pairs
            #pragma unroll
            for (int j = 0; j < 4; j++) {
                hr = __builtin_amdgcn_fdot2(Wr[4 * q + j], hp[j], hr, false);
                hz = __builtin_amdgcn_fdot2(Wz[4 * q + j], hp[j], hz, false);
                hn = __builtin_amdgcn_fdot2(Wn[4 * q + j], hp[j], hn, false);
            }
        }

        const float r = __builtin_amdgcn_rcpf(1.f + __expf(-(xr + hr)));
        const float z = __builtin_amdgcn_rcpf(1.f + __expf(-(xz + hz)));
        const float ny = xn + r * hn;
        const float n = 1.f - 2.f * __builtin_amdgcn_rcpf(1.f + __expf(2.f * ny));
        h = n + z * (h - n);                      // (1-z)*n + z*h, fp32 state
        hbuf[wv][ln] = (_Float16)h;               // f16 copy for next broadcast
    }

    out[row * HID + ln] = h;
}

extern "C" void kernel_launch(void* const* d_in, const int* in_sizes, int n_in,
                              void* d_out, int out_size, void* d_ws, size_t ws_size,
                              hipStream_t stream) {
    const int*   actor_ids  = (const int*)d_in[0];
    const int*   action_ids = (const int*)d_in[1];
    const int*   street_ids = (const int*)d_in[2];
    const float* bet        = (const float*)d_in[3];
    const int*   vmask      = (const int*)d_in[4];
    const float* E_actor    = (const float*)d_in[5];
    const float* E_action   = (const float*)d_in[6];
    const float* E_street   = (const float*)d_in[7];
    const float* W_proj     = (const float*)d_in[8];
    const float* b_proj     = (const float*)d_in[9];
    const float* W_ih       = (const float*)d_in[10];
    const float* W_hh       = (const float*)d_in[11];
    const float* b_ih       = (const float*)d_in[12];
    const float* b_hh       = (const float*)d_in[13];
    float*       out        = (float*)d_out;

    char* ws = (char*)d_ws;
    float*     tab   = (float*)(ws + WS_TAB);
    _Float16*  W16   = (_Float16*)(ws + WS_W16);
    int*       Lrow  = (int*)(ws + WS_LROW);
    int*       order = (int*)(ws + WS_ORDER);
    int*       hist  = (int*)(ws + WS_HIST);

    hipMemsetAsync(hist, 0, (TT + 1) * sizeof(int), stream);
    setup_tables<<<1, 256, 0, stream>>>(E_actor, E_action, E_street, W_proj,
                                        b_proj, W_ih, b_ih, W_hh, tab, W16);
    len_hist<<<NROWS / 4, 256, 0, stream>>>(vmask, Lrow, hist);
    scan_hist<<<1, 64, 0, stream>>>(hist);
    scatter_rows<<<NROWS / 256, 256, 0, stream>>>(Lrow, hist, order);
    gru_fused<<<NROWS / 4, 256, 0, stream>>>(actor_ids, action_ids, street_ids,
                                             bet, W16, b_hh, tab, order, Lrow, out);
}

// Round 5
// 203.996 us; speedup vs baseline: 2.0324x; 1.4959x over previous
//
#include <hip/hip_runtime.h>

#define HID 64
#define TT  128
#define NROWS 8192
#define NGRP (NROWS / 16)   // 512 groups of 16 length-sorted rows

typedef _Float16 half8 __attribute__((ext_vector_type(8)));
typedef float    f32x4 __attribute__((ext_vector_type(4)));

// d_ws byte layout:
//   WS_WF  : W_f A-tiles  f16 [12 tiles][64 lanes][8]      (K=32, zero-pad k>=21)
//   WS_WHH : W_hh A-tiles f16 [12 tiles][2 kt][64 lanes][8]
//   WS_BA  : 128 f32 fused bias (b_f + b_hh) for r,z gate rows
//   WS_BX  : 64 f32 b_f for n rows (input side)
//   WS_BH  : 64 f32 b_hh for n rows (recurrent side)
//   WS_EMB : f16 [17][8] embedding rows (7 actor / 4 action / 5 street+pad / 1 zero)
//   WS_LROW/WS_ORDER/WS_HIST : length sort scratch
#define WS_WF    0
#define WS_WHH   12288
#define WS_BA    36864
#define WS_BX    37376
#define WS_BH    37632
#define WS_EMB   37888
#define WS_LROW  38176
#define WS_ORDER 70944
#define WS_HIST  103712

// Fuse input path: W_f = W_ih * W_proj (192x21), b_f = b_ih + W_ih*b_proj.
// Emit MFMA A-layout tiles: A[m=lane&15][k=(lane>>4)*8+j].
__global__ __launch_bounds__(256) void setup_tables(
    const float* __restrict__ E_actor, const float* __restrict__ E_action,
    const float* __restrict__ E_street, const float* __restrict__ W_proj,
    const float* __restrict__ b_proj, const float* __restrict__ W_ih,
    const float* __restrict__ b_ih, const float* __restrict__ W_hh,
    const float* __restrict__ b_hh, char* __restrict__ ws)
{
    _Float16* WF  = (_Float16*)(ws + WS_WF);
    _Float16* WHH = (_Float16*)(ws + WS_WHH);
    float*    BA  = (float*)(ws + WS_BA);
    float*    BX  = (float*)(ws + WS_BX);
    float*    BH  = (float*)(ws + WS_BH);
    _Float16* EMB = (_Float16*)(ws + WS_EMB);

    const int j = threadIdx.x;   // gate row 0..191
    if (j < 192) {
        float wf[21];
        #pragma unroll
        for (int m = 0; m < 21; m++) wf[m] = 0.f;
        float bf = b_ih[j];
        for (int k = 0; k < 32; k++) {
            float w = W_ih[j * 32 + k];
            bf += w * b_proj[k];
            #pragma unroll
            for (int m = 0; m < 21; m++) wf[m] += w * W_proj[k * 21 + m];
        }
        if (j < 128) BA[j] = bf + b_hh[j];
        else { BX[j - 128] = bf; BH[j - 128] = b_hh[j]; }

        const int g3 = j / 64, rr = j % 64, w = rr / 16, m16 = rr & 15;
        const int T = g3 * 4 + w;
        // W_f tile (single K-tile, K=32 zero-padded)
        for (int k = 0; k < 32; k++) {
            int lane = m16 + 16 * (k >> 3), pos = k & 7;
            WF[(T * 64 + lane) * 8 + pos] = (k < 21) ? (_Float16)wf[k] : (_Float16)0.f;
        }
        // W_hh tiles (two K-tiles)
        for (int k = 0; k < 64; k++) {
            int kt = k >> 5, kk = k & 31;
            int lane = m16 + 16 * (kk >> 3), pos = kk & 7;
            WHH[((T * 2 + kt) * 64 + lane) * 8 + pos] = (_Float16)W_hh[j * HID + k];
        }
    }
    // embedding table rows: 0..6 actor, 7..10 action, 11..15 street(+pad), 16 zeros
    if (j < 17 * 8) {
        int r = j >> 3, m = j & 7;
        float v = 0.f;
        if (r < 7)       v = E_actor[r * 8 + m];
        else if (r < 11) v = E_action[(r - 7) * 8 + m];
        else if (r < 16) v = (m < 4) ? E_street[(r - 11) * 4 + m] : 0.f;
        EMB[j] = (_Float16)v;
    }
}

// per-row valid length via ballot popcount of the prefix mask + histogram
__global__ __launch_bounds__(256) void len_hist(
    const int* __restrict__ mask, int* __restrict__ Lrow, int* __restrict__ hist)
{
    const int wv = threadIdx.x >> 6, ln = threadIdx.x & 63;
    const int row = blockIdx.x * 4 + wv, base = row * TT;
    const int m0 = mask[base + ln], m1 = mask[base + 64 + ln];
    const int L = __popcll(__ballot(m0 != 0)) + __popcll(__ballot(m1 != 0));
    if (ln == 0) { Lrow[row] = L; atomicAdd(&hist[L], 1); }
}

// single block: exclusive scan of the 129-bin histogram in LDS, then counting-
// sort scatter (replaces R4's ~100us serial-global scan kernel)
__global__ __launch_bounds__(256) void scan_scatter(
    const int* __restrict__ Lrow, const int* __restrict__ hist,
    int* __restrict__ order)
{
    __shared__ int lh[TT + 1];
    const int tid = threadIdx.x;
    if (tid <= TT) lh[tid] = hist[tid];
    __syncthreads();
    if (tid == 0) {
        int run = 0;
        for (int i = 0; i <= TT; i++) { int t = lh[i]; lh[i] = run; run += t; }
    }
    __syncthreads();
    for (int r = tid; r < NROWS; r += 256) {
        int pos = atomicAdd(&lh[Lrow[r]], 1);
        order[pos] = r;
    }
}

// One block per 16-row group; 4 waves split the hidden dim (wave w: hid
// [16w,16w+16) = M-tiles {w,4+w,8+w}). Matvec + input path both via
// mfma_f32_16x16x32_f16 (A/B may live in AGPRs at zero cost). h: f32 master
// per lane, f16 LDS copy double-buffered for the B-frag, 1 barrier/step.
__global__ __launch_bounds__(256, 2) void gru_mfma(
    const int* __restrict__ actor_ids, const int* __restrict__ action_ids,
    const int* __restrict__ street_ids, const float* __restrict__ bet,
    const char* __restrict__ ws, const int* __restrict__ order,
    const int* __restrict__ Lrow, float* __restrict__ out)
{
    const _Float16* WF  = (const _Float16*)(ws + WS_WF);
    const _Float16* WHH = (const _Float16*)(ws + WS_WHH);
    const float*    BA  = (const float*)(ws + WS_BA);
    const float*    BX  = (const float*)(ws + WS_BX);
    const float*    BH  = (const float*)(ws + WS_BH);
    const _Float16* EMB = (const _Float16*)(ws + WS_EMB);

    __shared__ int2 pb[TT][16];                         // packed ids+bet, 16KB
    __shared__ __align__(16) _Float16 hb[2][16][80];    // h f16, dbuf, padded
    __shared__ __align__(16) _Float16 embl[17 * 8];

    const int tid = threadIdx.x;
    const int wv  = tid >> 6;         // wave = hid quarter
    const int l   = tid & 63;
    const int q   = l >> 4;           // quad
    const int n   = l & 15;           // batch col within group

    // long/short pairing for tail balance (groups sorted ascending by L)
    const int b = blockIdx.x;
    const int g = (b & 1) ? (NGRP - 1 - (b >> 1)) : (b >> 1);

    if (tid < 17 * 8) embl[tid] = EMB[tid];
    for (int i = tid; i < 2 * 16 * 80; i += 256) ((_Float16*)hb)[i] = (_Float16)0.f;
    // stage ids: 16 threads per row, coalesced over t
    {
        const int r = tid >> 4, tl = tid & 15;
        const int rowr = order[g * 16 + r];
        const int base = rowr * TT;
        #pragma unroll
        for (int i = 0; i < 8; i++) {
            int t = tl + 16 * i;
            int a = actor_ids[base + t], c = action_ids[base + t], s = street_ids[base + t];
            float f = bet[base + t];
            pb[t][r] = make_int2(a | (c << 3) | (s << 5), __float_as_int(f));
        }
    }

    // per-wave A-fragments (loop-invariant; AGPR-resident is fine for MFMA)
    half8 Af[3], Ah[3][2];
    #pragma unroll
    for (int g3 = 0; g3 < 3; g3++) {
        const int T = g3 * 4 + wv;
        Af[g3]    = *(const half8*)&WF[(T * 64 + l) * 8];
        Ah[g3][0] = *(const half8*)&WHH[((T * 2 + 0) * 64 + l) * 8];
        Ah[g3][1] = *(const half8*)&WHH[((T * 2 + 1) * 64 + l) * 8];
    }
    f32x4 biasR, biasZ, biasX4, biasH4;
    #pragma unroll
    for (int e = 0; e < 4; e++) {
        const int idx = 16 * wv + q * 4 + e;
        biasR[e]  = BA[idx];
        biasZ[e]  = BA[64 + idx];
        biasX4[e] = BX[idx];
        biasH4[e] = BH[idx];
    }

    const int myrow = order[g * 16 + n];
    const int Ln    = Lrow[myrow];
    const int Lmax  = __shfl(Ln, 15);    // ascending sort -> lane 15 holds max
    const bool isq2 = (q == 2);

    float h[4] = {0.f, 0.f, 0.f, 0.f};
    __syncthreads();

    for (int t = 0; t < Lmax; t++) {
        const int buf = t & 1;
        const int2 p = pb[t][n];
        const float betv = __int_as_float(p.y);
        const int a = p.x & 7, c = (p.x >> 3) & 3, s = (p.x >> 5) & 7;
        // feats B-frag: quad0 actor, quad1 action, quad2 street+bet, quad3 zeros
        const int eidx = (q == 0) ? a : (q == 1) ? (7 + c) : isq2 ? (11 + s) : 16;
        half8 Bf = *(const half8*)&embl[eidx * 8];
        {   // patch bet at k=20 (element 4) on quad2
            uint4* bu = (uint4*)&Bf;
            _Float16 b2[2] = {(_Float16)betv, (_Float16)0.f};
            unsigned bp = *(unsigned*)b2;
            bu->z = isq2 ? bp : bu->z;
        }
        const half8 Bh0 = *(const half8*)&hb[buf][n][q * 8];
        const half8 Bh1 = *(const half8*)&hb[buf][n][32 + q * 8];

        f32x4 aR = __builtin_amdgcn_mfma_f32_16x16x32_f16(Ah[0][0], Bh0, biasR, 0, 0, 0);
        aR = __builtin_amdgcn_mfma_f32_16x16x32_f16(Ah[0][1], Bh1, aR, 0, 0, 0);
        aR = __builtin_amdgcn_mfma_f32_16x16x32_f16(Af[0],   Bf,  aR, 0, 0, 0);
        f32x4 aZ = __builtin_amdgcn_mfma_f32_16x16x32_f16(Ah[1][0], Bh0, biasZ, 0, 0, 0);
        aZ = __builtin_amdgcn_mfma_f32_16x16x32_f16(Ah[1][1], Bh1, aZ, 0, 0, 0);
        aZ = __builtin_amdgcn_mfma_f32_16x16x32_f16(Af[1],   Bf,  aZ, 0, 0, 0);
        f32x4 aH = __builtin_amdgcn_mfma_f32_16x16x32_f16(Ah[2][0], Bh0, biasH4, 0, 0, 0);
        aH = __builtin_amdgcn_mfma_f32_16x16x32_f16(Ah[2][1], Bh1, aH, 0, 0, 0);
        f32x4 aX = __builtin_amdgcn_mfma_f32_16x16x32_f16(Af[2],   Bf,  biasX4, 0, 0, 0);

        const bool live = (t < Ln);
        #pragma unroll
        for (int e = 0; e < 4; e++) {
            const float r = __builtin_amdgcn_rcpf(1.f + __expf(-aR[e]));
            const float z = __builtin_amdgcn_rcpf(1.f + __expf(-aZ[e]));
            const float y = aX[e] + r * aH[e];
            const float nn = 1.f - 2.f * __builtin_amdgcn_rcpf(1.f + __expf(2.f * y));
            const float hn2 = nn + z * (h[e] - nn);
            h[e] = live ? hn2 : h[e];
        }
        // write f16 copy for next step's B-frag: 4 consecutive hid at 16wv+4q
        {
            _Float16 hp[4];
            #pragma unroll
            for (int e = 0; e < 4; e++) hp[e] = (_Float16)h[e];
            *(uint2*)&hb[buf ^ 1][n][16 * wv + 4 * q] = *(uint2*)hp;
        }
        __syncthreads();
    }

    // output: out[myrow][16wv+4q .. +4)
    float4 o = make_float4(h[0], h[1], h[2], h[3]);
    *(float4*)&out[myrow * HID + 16 * wv + 4 * q] = o;
}

extern "C" void kernel_launch(void* const* d_in, const int* in_sizes, int n_in,
                              void* d_out, int out_size, void* d_ws, size_t ws_size,
                              hipStream_t stream) {
    const int*   actor_ids  = (const int*)d_in[0];
    const int*   action_ids = (const int*)d_in[1];
    const int*   street_ids = (const int*)d_in[2];
    const float* bet        = (const float*)d_in[3];
    const int*   vmask      = (const int*)d_in[4];
    const float* E_actor    = (const float*)d_in[5];
    const float* E_action   = (const float*)d_in[6];
    const float* E_street   = (const float*)d_in[7];
    const float* W_proj     = (const float*)d_in[8];
    const float* b_proj     = (const float*)d_in[9];
    const float* W_ih       = (const float*)d_in[10];
    const float* W_hh       = (const float*)d_in[11];
    const float* b_ih       = (const float*)d_in[12];
    const float* b_hh       = (const float*)d_in[13];
    float*       out        = (float*)d_out;

    char* ws = (char*)d_ws;
    int*  Lrow  = (int*)(ws + WS_LROW);
    int*  order = (int*)(ws + WS_ORDER);
    int*  hist  = (int*)(ws + WS_HIST);

    hipMemsetAsync(hist, 0, (TT + 1) * sizeof(int), stream);
    setup_tables<<<1, 256, 0, stream>>>(E_actor, E_action, E_street, W_proj,
                                        b_proj, W_ih, b_ih, W_hh, b_hh, ws);
    len_hist<<<NROWS / 4, 256, 0, stream>>>(vmask, Lrow, hist);
    scan_scatter<<<1, 256, 0, stream>>>(Lrow, hist, order);
    gru_mfma<<<NGRP, 256, 0, stream>>>(actor_ids, action_ids, street_ids, bet,
                                       ws, order, Lrow, out);
}